// Round 8
// baseline (79.785 us; speedup 1.0000x reference)
//
#include <hip/hip_runtime.h>

#define BSZ 32
#define NN 512
#define INF 256
#define OUTF 128
#define NH 4
#define HD 512
#define NEG_SLOPE 0.2f

typedef __attribute__((ext_vector_type(8))) short bf16x8;
typedef __attribute__((ext_vector_type(8))) unsigned short ushort8;
typedef __attribute__((ext_vector_type(4))) float f32x4;

static __device__ __forceinline__ unsigned short f2bf(float f) {
    unsigned u = __builtin_bit_cast(unsigned, f);
    return (unsigned short)((u + 0x7FFFu + ((u >> 16) & 1u)) >> 16);
}

static __device__ __forceinline__ bf16x8 pk8(float4 a, float4 b) {
    unsigned d0, d1, d2, d3;
    asm("v_cvt_pk_bf16_f32 %0, %1, %2" : "=v"(d0) : "v"(a.x), "v"(a.y));
    asm("v_cvt_pk_bf16_f32 %0, %1, %2" : "=v"(d1) : "v"(a.z), "v"(a.w));
    asm("v_cvt_pk_bf16_f32 %0, %1, %2" : "=v"(d2) : "v"(b.x), "v"(b.y));
    asm("v_cvt_pk_bf16_f32 %0, %1, %2" : "=v"(d3) : "v"(b.z), "v"(b.w));
    uint4 u; u.x = d0; u.y = d1; u.z = d2; u.w = d3;
    return __builtin_bit_cast(bf16x8, u);
}

// ---- pack w[256][512] -> wB frag layout ((kb*4+g)*512 + c)*8 + e, k=kb*32+g*8+e ----
__global__ __launch_bounds__(256) void kpack_w(const float* __restrict__ w,
                                               unsigned short* __restrict__ wB) {
    int gid = blockIdx.x * 256 + threadIdx.x;
    int c = gid & 511, k = gid >> 9;
    int kb = k >> 5, g = (k >> 3) & 3, e = k & 7;
    wB[(((size_t)(kb * 4 + g) * 512) + c) * 8 + e] = f2bf(w[(size_t)k * 512 + c]);
}

// ---- projection GEMM (MFMA): 16 rows/block, 1024 blocks; coeffs; hB staged ----
__global__ __launch_bounds__(256) void k_proj(
    const float* __restrict__ x, const unsigned short* __restrict__ wB,
    const float* __restrict__ ai, const float* __restrict__ aj,
    unsigned short* __restrict__ hB, float* __restrict__ ciT, float* __restrict__ cjT)
{
    __shared__ unsigned short hs[NH * 2048];           // 16 KB, half-slab image
    const int tid = threadIdx.x;
    const int lane = tid & 63, head = tid >> 6;
    const int l15 = lane & 15, g = lane >> 4;
    const int row0 = blockIdx.x * 16;

    f32x4 acc[8] = {};
    const float* xp = x + (size_t)(row0 + l15) * INF + g * 8;
    const unsigned short* bp = wB + ((size_t)g * 512 + head * 128 + l15) * 8;

    #pragma unroll
    for (int kb = 0; kb < 8; ++kb) {
        float4 f0 = *(const float4*)(xp + kb * 32);
        float4 f1 = *(const float4*)(xp + kb * 32 + 4);
        bf16x8 a0 = pk8(f0, f1);
        #pragma unroll
        for (int nf = 0; nf < 8; ++nf) {
            bf16x8 bv = *(const bf16x8*)(bp + (size_t)kb * 16384 + nf * 128);
            acc[nf] = __builtin_amdgcn_mfma_f32_16x16x32_bf16(a0, bv, acc[nf], 0, 0, 0);
        }
    }

    float aiv[8], ajv[8];
    #pragma unroll
    for (int nf = 0; nf < 8; ++nf) {
        aiv[nf] = ai[head * 128 + nf * 16 + l15];
        ajv[nf] = aj[head * 128 + nf * 16 + l15];
    }
    const int b = row0 >> 9;
    const int nloc0 = row0 & 511;
    const int kb2 = nloc0 >> 5;
    const int g2base = (nloc0 >> 3) & 3;               // 0 or 2

    {   // coeffs: reduce over l15 (d-dim), rows n = nloc0 + 4g + reg
        float pi[4] = {0,0,0,0}, pj[4] = {0,0,0,0};
        #pragma unroll
        for (int nf = 0; nf < 8; ++nf)
            #pragma unroll
            for (int reg = 0; reg < 4; ++reg) {
                pi[reg] = fmaf(acc[nf][reg], aiv[nf], pi[reg]);
                pj[reg] = fmaf(acc[nf][reg], ajv[nf], pj[reg]);
            }
        #pragma unroll
        for (int reg = 0; reg < 4; ++reg) {
            #pragma unroll
            for (int off = 1; off < 16; off <<= 1) {
                pi[reg] += __shfl_xor(pi[reg], off);
                pj[reg] += __shfl_xor(pj[reg], off);
            }
        }
        if (l15 == 0) {
            #pragma unroll
            for (int reg = 0; reg < 4; ++reg) {
                int n = nloc0 + 4 * g + reg;
                ciT[((size_t)(head * BSZ + b) * NN) + n] = pi[reg];
                cjT[((size_t)(head * BSZ + b) * NN) + n] = pj[reg];
            }
        }
        // stage hB half-slab: jloc = 4g+reg in [0,16); local g2l = jloc>>3
        #pragma unroll
        for (int reg = 0; reg < 4; ++reg) {
            int jloc = 4 * g + reg;
            int g2l = jloc >> 3, e = jloc & 7;
            #pragma unroll
            for (int nf = 0; nf < 8; ++nf)
                hs[head * 2048 + (g2l * 128 + nf * 16 + l15) * 8 + e] =
                    f2bf(acc[nf][reg]);
        }
    }
    __syncthreads();
    {   // per head: contiguous 4 KB half-slab (2048 shorts = 256 ushort8) -> hB
        ushort8* dst = (ushort8*)(hB +
            ((((size_t)(b * 4 + head) * 16 + kb2) * 4 + g2base) * 1024));
        const ushort8* src = (const ushort8*)(hs + head * 2048);
        #pragma unroll
        for (int it = 0; it < 4; ++it)               // FIX: was 2 iters (half-copy)
            dst[it * 64 + lane] = src[it * 64 + lane];
    }
}

// ---- fused attention: per-lane P synthesis in A-frag layout, no LDS round-trip.
// 1024 blocks (4/CU), wave = 1 head x 1 i-tile (16 rows). Ones-MFMA row sums.
__global__ __launch_bounds__(256) void k_attn(
    const float* __restrict__ adj, const unsigned short* __restrict__ hB,
    const float* __restrict__ ciT, const float* __restrict__ cjT,
    const float* __restrict__ bias, float* __restrict__ out)
{
    __shared__ __align__(16) float cj_s[NH][NN];   // 8 KB
    __shared__ float ci_s[NH][16];
    __shared__ unsigned maskw[16][17];             // padded, conflict-free
    __shared__ float M_s[NH];

    const int tid = threadIdx.x;
    const int lane = tid & 63, h = tid >> 6;
    const int l15 = lane & 15, g = lane >> 4;

    const int orig = blockIdx.x;                   // 1024 blocks, 1024%8==0
    const int swz = (orig & 7) * 128 + (orig >> 3);// XCD chunking: 4 b's per XCD
    const int b = swz >> 5;
    const int i0 = (swz & 31) * 16;

    {   // cj for this head + unmasked max (stabilizer upper bound)
        const float* src = cjT + (size_t)(h * BSZ + b) * NN;
        float mv = -1e30f;
        #pragma unroll
        for (int c = 0; c < 8; ++c) {
            float v = src[c * 64 + lane];
            cj_s[h][c * 64 + lane] = v;
            mv = fmaxf(mv, v);
        }
        #pragma unroll
        for (int off = 32; off; off >>= 1) mv = fmaxf(mv, __shfl_xor(mv, off));
        if (lane == 0) M_s[h] = mv;
        if (lane < 16) ci_s[h][lane] = ciT[(size_t)(h * BSZ + b) * NN + i0 + lane];
    }
    // adjacency -> 32-bit mask words; wave h builds rows h*4..h*4+3
    #pragma unroll
    for (int rr = 0; rr < 4; ++rr) {
        int r = h * 4 + rr;
        const float* arow = adj + (size_t)(b * NN + i0 + r) * NN;
        #pragma unroll
        for (int t = 0; t < 8; ++t) {
            unsigned long long msk = __ballot(arow[t * 64 + lane] > 0.f);
            if (lane == 0) {
                maskw[r][2 * t]     = (unsigned)msk;
                maskw[r][2 * t + 1] = (unsigned)(msk >> 32);
            }
        }
    }
    __syncthreads();

    const float Mh = M_s[h];
    const float bc = ci_s[h][l15];                 // this lane's A-row ci
    float sm = bc + Mh;
    const float mrow = fmaxf(sm, NEG_SLOPE * sm);  // upper bound of row's scores

    float bv[8];
    #pragma unroll
    for (int nf = 0; nf < 8; ++nf) bv[nf] = bias[h * 128 + nf * 16 + l15];

    bf16x8 ones;
    #pragma unroll
    for (int e = 0; e < 8; ++e) ones[e] = (short)0x3F80;

    f32x4 acc[8] = {};
    f32x4 accs = {};
    const unsigned short* bp = hB + (size_t)(b * 4 + h) * 65536 + g * 1024 + l15 * 8;
    const float* cjh = cj_s[h];

    #pragma unroll 2
    for (int kb = 0; kb < 16; ++kb) {
        bf16x8 bf[8];
        #pragma unroll
        for (int nf = 0; nf < 8; ++nf)
            bf[nf] = *(const bf16x8*)(bp + (size_t)kb * 4096 + nf * 128);

        float4 cva = *(const float4*)&cjh[kb * 32 + g * 8];
        float4 cvb = *(const float4*)&cjh[kb * 32 + g * 8 + 4];
        float cj8[8] = {cva.x, cva.y, cva.z, cva.w, cvb.x, cvb.y, cvb.z, cvb.w};

        unsigned byte = (maskw[l15][kb] >> (g * 8)) & 0xFFu;
        float p[8];
        #pragma unroll
        for (int e = 0; e < 8; ++e) {
            float s = bc + cj8[e];
            s = fmaxf(s, NEG_SLOPE * s);
            float pe = __expf(s - mrow);
            p[e] = ((byte >> e) & 1u) ? pe : 0.f;
        }
        unsigned d0, d1, d2, d3;
        asm("v_cvt_pk_bf16_f32 %0, %1, %2" : "=v"(d0) : "v"(p[0]), "v"(p[1]));
        asm("v_cvt_pk_bf16_f32 %0, %1, %2" : "=v"(d1) : "v"(p[2]), "v"(p[3]));
        asm("v_cvt_pk_bf16_f32 %0, %1, %2" : "=v"(d2) : "v"(p[4]), "v"(p[5]));
        asm("v_cvt_pk_bf16_f32 %0, %1, %2" : "=v"(d3) : "v"(p[6]), "v"(p[7]));
        uint4 u; u.x = d0; u.y = d1; u.z = d2; u.w = d3;
        bf16x8 av = __builtin_bit_cast(bf16x8, u);

        #pragma unroll
        for (int nf = 0; nf < 8; ++nf)
            acc[nf] = __builtin_amdgcn_mfma_f32_16x16x32_bf16(av, bf[nf], acc[nf], 0, 0, 0);
        accs = __builtin_amdgcn_mfma_f32_16x16x32_bf16(av, ones, accs, 0, 0, 0);
    }

    #pragma unroll
    for (int reg = 0; reg < 4; ++reg) {
        float sum = accs[reg];
        float inv = sum > 0.f ? 1.f / sum : 0.f;
        const int i = i0 + g * 4 + reg;            // D row = g*4+reg
        #pragma unroll
        for (int nf = 0; nf < 8; ++nf) {
            int colg = h * 128 + nf * 16 + l15;
            out[(size_t)(b * NN + i) * HD + colg] = acc[nf][reg] * inv + bv[nf];
        }
    }
}

extern "C" void kernel_launch(void* const* d_in, const int* in_sizes, int n_in,
                              void* d_out, int out_size, void* d_ws, size_t ws_size,
                              hipStream_t stream)
{
    const float* x    = (const float*)d_in[0];
    const float* adj  = (const float*)d_in[1];
    const float* w    = (const float*)d_in[2];
    const float* ai   = (const float*)d_in[3];
    const float* aj   = (const float*)d_in[4];
    const float* bias = (const float*)d_in[5];
    float* out = (float*)d_out;

    char* ws = (char*)d_ws;
    unsigned short* wB = (unsigned short*)ws;                       //   262,144 B
    unsigned short* hB = (unsigned short*)(ws + 262144);            // 16,777,216 B
    float* ciT         = (float*)(ws + 17039360);                   //   262,144 B
    float* cjT         = (float*)(ws + 17301504);                   //   262,144 B

    kpack_w<<<512, 256, 0, stream>>>(w, wB);
    k_proj<<<BSZ * NN / 16, 256, 0, stream>>>(x, wB, ai, aj, hB, ciT, cjT);
    k_attn<<<BSZ * (NN / 16), 256, 0, stream>>>(adj, hB, ciT, cjT, bias, out);
}

// Round 9
// 60.187 us; speedup vs baseline: 1.3256x; 1.3256x over previous
//
#include <hip/hip_runtime.h>

#define BSZ 32
#define NN 512
#define INF 256
#define NH 4
#define HD 512
#define NEG_SLOPE 0.2f

typedef __attribute__((ext_vector_type(8))) short bf16x8;
typedef __attribute__((ext_vector_type(8))) unsigned short ushort8;
typedef __attribute__((ext_vector_type(4))) float f32x4;

static __device__ __forceinline__ unsigned short f2bf(float f) {
    unsigned u = __builtin_bit_cast(unsigned, f);
    return (unsigned short)((u + 0x7FFFu + ((u >> 16) & 1u)) >> 16);
}

static __device__ __forceinline__ bf16x8 pk8(float4 a, float4 b) {
    unsigned d0, d1, d2, d3;
    asm("v_cvt_pk_bf16_f32 %0, %1, %2" : "=v"(d0) : "v"(a.x), "v"(a.y));
    asm("v_cvt_pk_bf16_f32 %0, %1, %2" : "=v"(d1) : "v"(a.z), "v"(a.w));
    asm("v_cvt_pk_bf16_f32 %0, %1, %2" : "=v"(d2) : "v"(b.x), "v"(b.y));
    asm("v_cvt_pk_bf16_f32 %0, %1, %2" : "=v"(d3) : "v"(b.z), "v"(b.w));
    uint4 u; u.x = d0; u.y = d1; u.z = d2; u.w = d3;
    return __builtin_bit_cast(bf16x8, u);
}

static __device__ __forceinline__ void gl_lds16(const void* g, void* l) {
    __builtin_amdgcn_global_load_lds(
        (const __attribute__((address_space(1))) unsigned int*)g,
        (__attribute__((address_space(3))) unsigned int*)l, 16, 0, 0);
}

// ---- pack w[256][512] -> wB frag layout ((kb*4+g)*512 + c)*8 + e, k=kb*32+g*8+e ----
__global__ __launch_bounds__(256) void kpack_w(const float* __restrict__ w,
                                               unsigned short* __restrict__ wB) {
    int gid = blockIdx.x * 256 + threadIdx.x;
    int c = gid & 511, k = gid >> 9;
    int kb = k >> 5, g = (k >> 3) & 3, e = k & 7;
    wB[(((size_t)(kb * 4 + g) * 512) + c) * 8 + e] = f2bf(w[(size_t)k * 512 + c]);
}

// ---- projection GEMM (MFMA): 16 rows/block; coeffs; adj->bitmask; hB staged.
// hB slab layout per (b,h,kb): shorts [(nf*4+g)*16 + l15]*8 + e  (d=nf*16+l15,
// j=kb*32+g*8+e) => B-frag ds_read/global read = base + lane*16 (conflict-free).
__global__ __launch_bounds__(256) void k_proj(
    const float* __restrict__ x, const float* __restrict__ adj,
    const unsigned short* __restrict__ wB,
    const float* __restrict__ ai, const float* __restrict__ aj,
    unsigned short* __restrict__ hB, float* __restrict__ ciT,
    float* __restrict__ cjT, unsigned* __restrict__ mb)
{
    __shared__ unsigned short hs[NH * 2048];           // 16 KB half-slab image
    const int tid = threadIdx.x;
    const int lane = tid & 63, head = tid >> 6;
    const int l15 = lane & 15, g = lane >> 4;
    const int row0 = blockIdx.x * 16;

    // adjacency -> bitmask buffer (once per row, device-wide); overlaps MFMA fill
    #pragma unroll
    for (int rr = 0; rr < 4; ++rr) {
        int r = head * 4 + rr;
        const float* arow = adj + (size_t)(row0 + r) * NN;
        #pragma unroll
        for (int t = 0; t < 8; ++t) {
            unsigned long long msk = __ballot(arow[t * 64 + lane] > 0.f);
            if (lane == 0) {
                mb[((size_t)row0 + r) * 16 + 2 * t]     = (unsigned)msk;
                mb[((size_t)row0 + r) * 16 + 2 * t + 1] = (unsigned)(msk >> 32);
            }
        }
    }

    f32x4 acc[8] = {};
    const float* xp = x + (size_t)(row0 + l15) * INF + g * 8;
    const unsigned short* bp = wB + ((size_t)g * 512 + head * 128 + l15) * 8;

    #pragma unroll
    for (int kb = 0; kb < 8; ++kb) {
        float4 f0 = *(const float4*)(xp + kb * 32);
        float4 f1 = *(const float4*)(xp + kb * 32 + 4);
        bf16x8 a0 = pk8(f0, f1);
        #pragma unroll
        for (int nf = 0; nf < 8; ++nf) {
            bf16x8 bv = *(const bf16x8*)(bp + (size_t)kb * 16384 + nf * 128);
            acc[nf] = __builtin_amdgcn_mfma_f32_16x16x32_bf16(a0, bv, acc[nf], 0, 0, 0);
        }
    }

    float aiv[8], ajv[8];
    #pragma unroll
    for (int nf = 0; nf < 8; ++nf) {
        aiv[nf] = ai[head * 128 + nf * 16 + l15];
        ajv[nf] = aj[head * 128 + nf * 16 + l15];
    }
    const int b = row0 >> 9;
    const int nloc0 = row0 & 511;
    const int kb2 = nloc0 >> 5;
    const int g2base = (nloc0 >> 3) & 3;               // 0 or 2

    {   // coeffs
        float pi[4] = {0,0,0,0}, pj[4] = {0,0,0,0};
        #pragma unroll
        for (int nf = 0; nf < 8; ++nf)
            #pragma unroll
            for (int reg = 0; reg < 4; ++reg) {
                pi[reg] = fmaf(acc[nf][reg], aiv[nf], pi[reg]);
                pj[reg] = fmaf(acc[nf][reg], ajv[nf], pj[reg]);
            }
        #pragma unroll
        for (int reg = 0; reg < 4; ++reg) {
            #pragma unroll
            for (int off = 1; off < 16; off <<= 1) {
                pi[reg] += __shfl_xor(pi[reg], off);
                pj[reg] += __shfl_xor(pj[reg], off);
            }
        }
        if (l15 == 0) {
            #pragma unroll
            for (int reg = 0; reg < 4; ++reg) {
                int n = nloc0 + 4 * g + reg;
                ciT[((size_t)(head * BSZ + b) * NN) + n] = pi[reg];
                cjT[((size_t)(head * BSZ + b) * NN) + n] = pj[reg];
            }
        }
        // stage half-slab in NEW layout: local short idx = nf*256 + g2l*128 + l15*8 + e
        #pragma unroll
        for (int reg = 0; reg < 4; ++reg) {
            int jloc = 4 * g + reg;
            int g2l = jloc >> 3, e = jloc & 7;
            #pragma unroll
            for (int nf = 0; nf < 8; ++nf)
                hs[head * 2048 + nf * 256 + g2l * 128 + l15 * 8 + e] =
                    f2bf(acc[nf][reg]);
        }
    }
    __syncthreads();
    {   // copy: dst ushort8 idx = nf*64 + g2base*16 + w  (w = g2l*16+l15 in [0,32))
        ushort8* dst = (ushort8*)(hB + (((size_t)(b * 4 + head) * 16 + kb2) * 4096));
        const ushort8* src = (const ushort8*)(hs + head * 2048);
        #pragma unroll
        for (int it = 0; it < 4; ++it) {
            int u = it * 64 + lane;                    // 256 ushort8 per head
            int nf = u >> 5, wdx = u & 31;
            dst[nf * 64 + g2base * 16 + wdx] = src[u];
        }
    }
}

// ---- fused attention: block = (b, head, 64 rows). B-slab staged once in LDS
// (double-buffered, global_load_lds) and shared by 4 waves. Per-lane P synthesis
// in A-frag layout; ones-MFMA row sums; 1/sum in epilogue.
__global__ __launch_bounds__(256, 4) void k_attn(
    const unsigned short* __restrict__ hB, const float* __restrict__ ciT,
    const float* __restrict__ cjT, const unsigned* __restrict__ mb,
    const float* __restrict__ bias, float* __restrict__ out)
{
    __shared__ __align__(16) unsigned short Bst[2][4096];  // 16 KB double buffer
    __shared__ __align__(16) float cjh[NN];                // 2 KB
    __shared__ float cih[64];
    __shared__ unsigned maskS[64][17];                     // padded (17 odd)
    __shared__ float Mpart[4];

    const int tid = threadIdx.x;
    const int lane = tid & 63, wave = tid >> 6;
    const int l15 = lane & 15, g = lane >> 4;

    const int orig = blockIdx.x;                   // 1024 blocks, bijective
    const int swz = (orig & 7) * 128 + (orig >> 3);// XCD x -> b in {4x..4x+3}
    const int b  = swz >> 5;
    const int h  = (swz >> 3) & 3;
    const int i0 = (swz & 7) * 64;

    const char* gslab = (const char*)(hB + (size_t)(b * NH + h) * 65536);

    // stage kb=0 (linear copy: wave w covers bytes [w*2048, w*2048+2048))
    gl_lds16(gslab + wave * 2048 + lane * 16,        (char*)&Bst[0][0] + wave * 2048);
    gl_lds16(gslab + wave * 2048 + 1024 + lane * 16, (char*)&Bst[0][0] + wave * 2048 + 1024);

    {   // cj -> LDS + unmasked max (stabilizer upper bound)
        const float* src = cjT + (size_t)(h * BSZ + b) * NN;
        float v0 = src[tid], v1 = src[tid + 256];
        cjh[tid] = v0; cjh[tid + 256] = v1;
        float mv = fmaxf(v0, v1);
        #pragma unroll
        for (int off = 32; off; off >>= 1) mv = fmaxf(mv, __shfl_xor(mv, off));
        if (lane == 0) Mpart[wave] = mv;
        if (tid < 64) cih[tid] = ciT[(size_t)(h * BSZ + b) * NN + i0 + tid];
        // masks: 64 rows x 16 words = 4 KB, uint4 per thread
        uint4 m4 = ((const uint4*)(mb + ((size_t)b * NN + i0) * 16))[tid];
        int base = tid * 4, row = base >> 4, wi = base & 15;
        maskS[row][wi] = m4.x; maskS[row][wi + 1] = m4.y;
        maskS[row][wi + 2] = m4.z; maskS[row][wi + 3] = m4.w;
    }
    __syncthreads();   // drains stage-0 vmcnt too

    const float M = fmaxf(fmaxf(Mpart[0], Mpart[1]), fmaxf(Mpart[2], Mpart[3]));
    const float bc = cih[wave * 16 + l15];         // this lane's A-row ci
    float smx = bc + M;
    const float mrow = fmaxf(smx, NEG_SLOPE * smx);

    float bvv[8];
    #pragma unroll
    for (int nf = 0; nf < 8; ++nf) bvv[nf] = bias[h * 128 + nf * 16 + l15];

    bf16x8 ones;
    #pragma unroll
    for (int e = 0; e < 8; ++e) ones[e] = (short)0x3F80;

    f32x4 acc[8] = {};
    f32x4 accs = {};
    int cur = 0;
    const unsigned* mrowp = maskS[wave * 16 + l15];

    for (int kb = 0; kb < 16; ++kb) {
        if (kb < 15) {   // prefetch next slab into other buffer
            const char* gs = gslab + (size_t)(kb + 1) * 8192 + wave * 2048 + lane * 16;
            char* ld = (char*)&Bst[cur ^ 1][0] + wave * 2048;
            gl_lds16(gs, ld);
            gl_lds16(gs + 1024, ld + 1024);
        }

        // A-frag synthesis (VALU) — independent of B ds_reads
        float4 cva = *(const float4*)&cjh[kb * 32 + g * 8];
        float4 cvb = *(const float4*)&cjh[kb * 32 + g * 8 + 4];
        float cj8[8] = {cva.x, cva.y, cva.z, cva.w, cvb.x, cvb.y, cvb.z, cvb.w};
        unsigned byte = (mrowp[kb] >> (g * 8)) & 0xFFu;
        float p[8];
        #pragma unroll
        for (int e = 0; e < 8; ++e) {
            float s = bc + cj8[e];
            s = fmaxf(s, NEG_SLOPE * s);
            float pe = __expf(s - mrow);
            p[e] = ((byte >> e) & 1u) ? pe : 0.f;
        }
        unsigned d0, d1, d2, d3;
        asm("v_cvt_pk_bf16_f32 %0, %1, %2" : "=v"(d0) : "v"(p[0]), "v"(p[1]));
        asm("v_cvt_pk_bf16_f32 %0, %1, %2" : "=v"(d1) : "v"(p[2]), "v"(p[3]));
        asm("v_cvt_pk_bf16_f32 %0, %1, %2" : "=v"(d2) : "v"(p[4]), "v"(p[5]));
        asm("v_cvt_pk_bf16_f32 %0, %1, %2" : "=v"(d3) : "v"(p[6]), "v"(p[7]));
        uint4 u; u.x = d0; u.y = d1; u.z = d2; u.w = d3;
        bf16x8 av = __builtin_bit_cast(bf16x8, u);

        // B-frags from LDS: byte = nf*1024 + lane*16 (contiguous, conflict-free)
        const char* bb = (const char*)&Bst[cur][0] + lane * 16;
        bf16x8 bfr[8];
        #pragma unroll
        for (int nf = 0; nf < 8; ++nf)
            bfr[nf] = *(const bf16x8*)(bb + nf * 1024);

        #pragma unroll
        for (int nf = 0; nf < 8; ++nf)
            acc[nf] = __builtin_amdgcn_mfma_f32_16x16x32_bf16(av, bfr[nf], acc[nf], 0, 0, 0);
        accs = __builtin_amdgcn_mfma_f32_16x16x32_bf16(av, ones, accs, 0, 0, 0);

        if (kb < 15) { __syncthreads(); cur ^= 1; }
    }

    #pragma unroll
    for (int reg = 0; reg < 4; ++reg) {
        float sum = accs[reg];
        float inv = sum > 0.f ? 1.f / sum : 0.f;
        const int i = i0 + wave * 16 + g * 4 + reg;    // D row = g*4+reg
        #pragma unroll
        for (int nf = 0; nf < 8; ++nf) {
            int colg = h * 128 + nf * 16 + l15;
            out[(size_t)(b * NN + i) * HD + colg] = acc[nf][reg] * inv + bvv[nf];
        }
    }
}

extern "C" void kernel_launch(void* const* d_in, const int* in_sizes, int n_in,
                              void* d_out, int out_size, void* d_ws, size_t ws_size,
                              hipStream_t stream)
{
    const float* x    = (const float*)d_in[0];
    const float* adj  = (const float*)d_in[1];
    const float* w    = (const float*)d_in[2];
    const float* ai   = (const float*)d_in[3];
    const float* aj   = (const float*)d_in[4];
    const float* bias = (const float*)d_in[5];
    float* out = (float*)d_out;

    char* ws = (char*)d_ws;
    unsigned short* wB = (unsigned short*)ws;                       //   262,144 B
    unsigned short* hB = (unsigned short*)(ws + 262144);            // 16,777,216 B
    float* ciT         = (float*)(ws + 17039360);                   //   262,144 B
    float* cjT         = (float*)(ws + 17301504);                   //   262,144 B
    unsigned* mb       = (unsigned*)(ws + 17563648);                // 1,048,576 B

    kpack_w<<<512, 256, 0, stream>>>(w, wB);
    k_proj<<<BSZ * NN / 16, 256, 0, stream>>>(x, adj, wB, ai, aj, hB, ciT, cjT, mb);
    k_attn<<<BSZ * NH * (NN / 64), 256, 0, stream>>>(hB, ciT, cjT, mb, bias, out);
}

// Round 10
// 58.033 us; speedup vs baseline: 1.3748x; 1.0371x over previous
//
#include <hip/hip_runtime.h>

#define BSZ 32
#define NN 512
#define INF 256
#define NH 4
#define HD 512
#define NEG_SLOPE 0.2f

typedef __attribute__((ext_vector_type(8))) short bf16x8;
typedef __attribute__((ext_vector_type(8))) unsigned short ushort8;
typedef __attribute__((ext_vector_type(4))) float f32x4;

static __device__ __forceinline__ unsigned short f2bf(float f) {
    unsigned u = __builtin_bit_cast(unsigned, f);
    return (unsigned short)((u + 0x7FFFu + ((u >> 16) & 1u)) >> 16);
}

static __device__ __forceinline__ bf16x8 pk8(float4 a, float4 b) {
    unsigned d0, d1, d2, d3;
    asm("v_cvt_pk_bf16_f32 %0, %1, %2" : "=v"(d0) : "v"(a.x), "v"(a.y));
    asm("v_cvt_pk_bf16_f32 %0, %1, %2" : "=v"(d1) : "v"(a.z), "v"(a.w));
    asm("v_cvt_pk_bf16_f32 %0, %1, %2" : "=v"(d2) : "v"(b.x), "v"(b.y));
    asm("v_cvt_pk_bf16_f32 %0, %1, %2" : "=v"(d3) : "v"(b.z), "v"(b.w));
    uint4 u; u.x = d0; u.y = d1; u.z = d2; u.w = d3;
    return __builtin_bit_cast(bf16x8, u);
}

static __device__ __forceinline__ void gl_lds16(const void* g, void* l) {
    __builtin_amdgcn_global_load_lds(
        (const __attribute__((address_space(1))) unsigned int*)g,
        (__attribute__((address_space(3))) unsigned int*)l, 16, 0, 0);
}

// ---- pack w[256][512] -> wB frag layout ((kb*4+g)*512 + c)*8 + e, k=kb*32+g*8+e ----
__global__ __launch_bounds__(256) void kpack_w(const float* __restrict__ w,
                                               unsigned short* __restrict__ wB) {
    int gid = blockIdx.x * 256 + threadIdx.x;
    int c = gid & 511, k = gid >> 9;
    int kb = k >> 5, g = (k >> 3) & 3, e = k & 7;
    wB[(((size_t)(kb * 4 + g) * 512) + c) * 8 + e] = f2bf(w[(size_t)k * 512 + c]);
}

// ---- adjacency -> bitmask words (dedicated streaming kernel; 8 blocks/CU) ----
__global__ __launch_bounds__(256) void kmask(const float* __restrict__ adj,
                                             unsigned* __restrict__ mb) {
    const int lane = threadIdx.x & 63, wave = threadIdx.x >> 6;
    const int row0 = blockIdx.x * 8 + wave * 2;    // 2048 blocks x 4 waves x 2 rows
    #pragma unroll
    for (int rr = 0; rr < 2; ++rr) {
        const float* arow = adj + (size_t)(row0 + rr) * NN;
        #pragma unroll
        for (int t = 0; t < 8; ++t) {
            unsigned long long msk = __ballot(arow[t * 64 + lane] > 0.f);
            if (lane == 0) {
                mb[(size_t)(row0 + rr) * 16 + 2 * t]     = (unsigned)msk;
                mb[(size_t)(row0 + rr) * 16 + 2 * t + 1] = (unsigned)(msk >> 32);
            }
        }
    }
}

// ---- projection GEMM (MFMA): 16 rows/block; coeffs; hB staged wide stores.
// hB slab layout per (b,h,kb): shorts [(nf*4+g)*16 + l15]*8 + e  (d=nf*16+l15,
// j=kb*32+g*8+e) => B-frag read = base + lane*16 (contiguous, conflict-free).
__global__ __launch_bounds__(256) void k_proj(
    const float* __restrict__ x, const unsigned short* __restrict__ wB,
    const float* __restrict__ ai, const float* __restrict__ aj,
    unsigned short* __restrict__ hB, float* __restrict__ ciT, float* __restrict__ cjT)
{
    __shared__ unsigned short hs[NH * 2048];           // 16 KB half-slab image
    const int tid = threadIdx.x;
    const int lane = tid & 63, head = tid >> 6;
    const int l15 = lane & 15, g = lane >> 4;
    const int row0 = blockIdx.x * 16;

    f32x4 acc[8] = {};
    const float* xp = x + (size_t)(row0 + l15) * INF + g * 8;
    const unsigned short* bp = wB + ((size_t)g * 512 + head * 128 + l15) * 8;

    #pragma unroll
    for (int kb = 0; kb < 8; ++kb) {
        float4 f0 = *(const float4*)(xp + kb * 32);
        float4 f1 = *(const float4*)(xp + kb * 32 + 4);
        bf16x8 a0 = pk8(f0, f1);
        #pragma unroll
        for (int nf = 0; nf < 8; ++nf) {
            bf16x8 bv = *(const bf16x8*)(bp + (size_t)kb * 16384 + nf * 128);
            acc[nf] = __builtin_amdgcn_mfma_f32_16x16x32_bf16(a0, bv, acc[nf], 0, 0, 0);
        }
    }

    float aiv[8], ajv[8];
    #pragma unroll
    for (int nf = 0; nf < 8; ++nf) {
        aiv[nf] = ai[head * 128 + nf * 16 + l15];
        ajv[nf] = aj[head * 128 + nf * 16 + l15];
    }
    const int b = row0 >> 9;
    const int nloc0 = row0 & 511;
    const int kb2 = nloc0 >> 5;
    const int g2base = (nloc0 >> 3) & 3;               // 0 or 2

    {   // coeffs: reduce over l15 (d-dim), rows n = nloc0 + 4g + reg
        float pi[4] = {0,0,0,0}, pj[4] = {0,0,0,0};
        #pragma unroll
        for (int nf = 0; nf < 8; ++nf)
            #pragma unroll
            for (int reg = 0; reg < 4; ++reg) {
                pi[reg] = fmaf(acc[nf][reg], aiv[nf], pi[reg]);
                pj[reg] = fmaf(acc[nf][reg], ajv[nf], pj[reg]);
            }
        #pragma unroll
        for (int reg = 0; reg < 4; ++reg) {
            #pragma unroll
            for (int off = 1; off < 16; off <<= 1) {
                pi[reg] += __shfl_xor(pi[reg], off);
                pj[reg] += __shfl_xor(pj[reg], off);
            }
        }
        if (l15 == 0) {
            #pragma unroll
            for (int reg = 0; reg < 4; ++reg) {
                int n = nloc0 + 4 * g + reg;
                ciT[((size_t)(head * BSZ + b) * NN) + n] = pi[reg];
                cjT[((size_t)(head * BSZ + b) * NN) + n] = pj[reg];
            }
        }
        // stage half-slab: local short idx = nf*256 + g2l*128 + l15*8 + e
        #pragma unroll
        for (int reg = 0; reg < 4; ++reg) {
            int jloc = 4 * g + reg;
            int g2l = jloc >> 3, e = jloc & 7;
            #pragma unroll
            for (int nf = 0; nf < 8; ++nf)
                hs[head * 2048 + nf * 256 + g2l * 128 + l15 * 8 + e] =
                    f2bf(acc[nf][reg]);
        }
    }
    __syncthreads();
    {   // copy: dst ushort8 idx = nf*64 + g2base*16 + w  (w = g2l*16+l15 in [0,32))
        ushort8* dst = (ushort8*)(hB + (((size_t)(b * 4 + head) * 16 + kb2) * 4096));
        const ushort8* src = (const ushort8*)(hs + head * 2048);
        #pragma unroll
        for (int it = 0; it < 4; ++it) {
            int u = it * 64 + lane;                    // 256 ushort8 per head
            int nf = u >> 5, wdx = u & 31;
            dst[nf * 64 + g2base * 16 + wdx] = src[u];
        }
    }
}

// ---- fused attention: block = (b, head, 64 rows). B-slab staged once in LDS
// (double-buffered, global_load_lds) and shared by 4 waves. Per-lane P synthesis
// in A-frag layout; ones-MFMA row sums; 1/sum in epilogue.
__global__ __launch_bounds__(256, 4) void k_attn(
    const unsigned short* __restrict__ hB, const float* __restrict__ ciT,
    const float* __restrict__ cjT, const unsigned* __restrict__ mb,
    const float* __restrict__ bias, float* __restrict__ out)
{
    __shared__ __align__(16) unsigned short Bst[2][4096];  // 16 KB double buffer
    __shared__ __align__(16) float cjh[NN];                // 2 KB
    __shared__ float cih[64];
    __shared__ unsigned maskS[64][17];                     // padded (17 odd)
    __shared__ float Mpart[4];

    const int tid = threadIdx.x;
    const int lane = tid & 63, wave = tid >> 6;
    const int l15 = lane & 15, g = lane >> 4;

    const int orig = blockIdx.x;                   // 1024 blocks, bijective
    const int swz = (orig & 7) * 128 + (orig >> 3);// XCD x -> b in {4x..4x+3}
    const int b  = swz >> 5;
    const int h  = (swz >> 3) & 3;
    const int i0 = (swz & 7) * 64;

    const char* gslab = (const char*)(hB + (size_t)(b * NH + h) * 65536);

    // stage kb=0 (linear copy: wave w covers bytes [w*2048, w*2048+2048))
    gl_lds16(gslab + wave * 2048 + lane * 16,        (char*)&Bst[0][0] + wave * 2048);
    gl_lds16(gslab + wave * 2048 + 1024 + lane * 16, (char*)&Bst[0][0] + wave * 2048 + 1024);

    {   // cj -> LDS + unmasked max (stabilizer upper bound)
        const float* src = cjT + (size_t)(h * BSZ + b) * NN;
        float v0 = src[tid], v1 = src[tid + 256];
        cjh[tid] = v0; cjh[tid + 256] = v1;
        float mv = fmaxf(v0, v1);
        #pragma unroll
        for (int off = 32; off; off >>= 1) mv = fmaxf(mv, __shfl_xor(mv, off));
        if (lane == 0) Mpart[wave] = mv;
        if (tid < 64) cih[tid] = ciT[(size_t)(h * BSZ + b) * NN + i0 + tid];
        // masks: 64 rows x 16 words = 4 KB, uint4 per thread
        uint4 m4 = ((const uint4*)(mb + ((size_t)b * NN + i0) * 16))[tid];
        int base = tid * 4, row = base >> 4, wi = base & 15;
        maskS[row][wi] = m4.x; maskS[row][wi + 1] = m4.y;
        maskS[row][wi + 2] = m4.z; maskS[row][wi + 3] = m4.w;
    }
    __syncthreads();   // drains stage-0 vmcnt too

    const float M = fmaxf(fmaxf(Mpart[0], Mpart[1]), fmaxf(Mpart[2], Mpart[3]));
    const float bc = cih[wave * 16 + l15];         // this lane's A-row ci
    float smx = bc + M;
    const float mrow = fmaxf(smx, NEG_SLOPE * smx);

    float bvv[8];
    #pragma unroll
    for (int nf = 0; nf < 8; ++nf) bvv[nf] = bias[h * 128 + nf * 16 + l15];

    bf16x8 ones;
    #pragma unroll
    for (int e = 0; e < 8; ++e) ones[e] = (short)0x3F80;

    f32x4 acc[8] = {};
    f32x4 accs = {};
    int cur = 0;
    const unsigned* mrowp = maskS[wave * 16 + l15];

    for (int kb = 0; kb < 16; ++kb) {
        if (kb < 15) {   // prefetch next slab into other buffer
            const char* gs = gslab + (size_t)(kb + 1) * 8192 + wave * 2048 + lane * 16;
            char* ld = (char*)&Bst[cur ^ 1][0] + wave * 2048;
            gl_lds16(gs, ld);
            gl_lds16(gs + 1024, ld + 1024);
        }

        // A-frag synthesis (VALU) — independent of B ds_reads
        float4 cva = *(const float4*)&cjh[kb * 32 + g * 8];
        float4 cvb = *(const float4*)&cjh[kb * 32 + g * 8 + 4];
        float cj8[8] = {cva.x, cva.y, cva.z, cva.w, cvb.x, cvb.y, cvb.z, cvb.w};
        unsigned byte = (mrowp[kb] >> (g * 8)) & 0xFFu;
        float p[8];
        #pragma unroll
        for (int e = 0; e < 8; ++e) {
            float s = bc + cj8[e];
            s = fmaxf(s, NEG_SLOPE * s);
            float pe = __expf(s - mrow);
            p[e] = ((byte >> e) & 1u) ? pe : 0.f;
        }
        unsigned d0, d1, d2, d3;
        asm("v_cvt_pk_bf16_f32 %0, %1, %2" : "=v"(d0) : "v"(p[0]), "v"(p[1]));
        asm("v_cvt_pk_bf16_f32 %0, %1, %2" : "=v"(d1) : "v"(p[2]), "v"(p[3]));
        asm("v_cvt_pk_bf16_f32 %0, %1, %2" : "=v"(d2) : "v"(p[4]), "v"(p[5]));
        asm("v_cvt_pk_bf16_f32 %0, %1, %2" : "=v"(d3) : "v"(p[6]), "v"(p[7]));
        uint4 u; u.x = d0; u.y = d1; u.z = d2; u.w = d3;
        bf16x8 av = __builtin_bit_cast(bf16x8, u);

        // B-frags from LDS: byte = nf*1024 + lane*16 (contiguous, conflict-free)
        const char* bb = (const char*)&Bst[cur][0] + lane * 16;
        bf16x8 bfr[8];
        #pragma unroll
        for (int nf = 0; nf < 8; ++nf)
            bfr[nf] = *(const bf16x8*)(bb + nf * 1024);

        #pragma unroll
        for (int nf = 0; nf < 8; ++nf)
            acc[nf] = __builtin_amdgcn_mfma_f32_16x16x32_bf16(av, bfr[nf], acc[nf], 0, 0, 0);
        accs = __builtin_amdgcn_mfma_f32_16x16x32_bf16(av, ones, accs, 0, 0, 0);

        if (kb < 15) { __syncthreads(); cur ^= 1; }
    }

    #pragma unroll
    for (int reg = 0; reg < 4; ++reg) {
        float sum = accs[reg];
        float inv = sum > 0.f ? 1.f / sum : 0.f;
        const int i = i0 + wave * 16 + g * 4 + reg;    // D row = g*4+reg
        #pragma unroll
        for (int nf = 0; nf < 8; ++nf) {
            int colg = h * 128 + nf * 16 + l15;
            out[(size_t)(b * NN + i) * HD + colg] = acc[nf][reg] * inv + bvv[nf];
        }
    }
}

extern "C" void kernel_launch(void* const* d_in, const int* in_sizes, int n_in,
                              void* d_out, int out_size, void* d_ws, size_t ws_size,
                              hipStream_t stream)
{
    const float* x    = (const float*)d_in[0];
    const float* adj  = (const float*)d_in[1];
    const float* w    = (const float*)d_in[2];
    const float* ai   = (const float*)d_in[3];
    const float* aj   = (const float*)d_in[4];
    const float* bias = (const float*)d_in[5];
    float* out = (float*)d_out;

    char* ws = (char*)d_ws;
    unsigned short* wB = (unsigned short*)ws;                       //   262,144 B
    unsigned short* hB = (unsigned short*)(ws + 262144);            // 16,777,216 B
    float* ciT         = (float*)(ws + 17039360);                   //   262,144 B
    float* cjT         = (float*)(ws + 17301504);                   //   262,144 B
    unsigned* mb       = (unsigned*)(ws + 17563648);                // 1,048,576 B

    kpack_w<<<512, 256, 0, stream>>>(w, wB);
    kmask<<<BSZ * NN / 8, 256, 0, stream>>>(adj, mb);
    k_proj<<<BSZ * NN / 16, 256, 0, stream>>>(x, wB, ai, aj, hB, ciT, cjT);
    k_attn<<<BSZ * NH * (NN / 64), 256, 0, stream>>>(hB, ciT, cjT, mb, bias, out);
}

// Round 11
// 51.998 us; speedup vs baseline: 1.5344x; 1.1161x over previous
//
#include <hip/hip_runtime.h>

#define BSZ 32
#define NN 512
#define INF 256
#define NH 4
#define HD 512
#define NEG_SLOPE 0.2f

typedef __attribute__((ext_vector_type(8))) short bf16x8;
typedef __attribute__((ext_vector_type(8))) unsigned short ushort8;
typedef __attribute__((ext_vector_type(4))) float f32x4;

static __device__ __forceinline__ unsigned short f2bf(float f) {
    unsigned u = __builtin_bit_cast(unsigned, f);
    return (unsigned short)((u + 0x7FFFu + ((u >> 16) & 1u)) >> 16);
}

static __device__ __forceinline__ bf16x8 pk8(float4 a, float4 b) {
    unsigned d0, d1, d2, d3;
    asm("v_cvt_pk_bf16_f32 %0, %1, %2" : "=v"(d0) : "v"(a.x), "v"(a.y));
    asm("v_cvt_pk_bf16_f32 %0, %1, %2" : "=v"(d1) : "v"(a.z), "v"(a.w));
    asm("v_cvt_pk_bf16_f32 %0, %1, %2" : "=v"(d2) : "v"(b.x), "v"(b.y));
    asm("v_cvt_pk_bf16_f32 %0, %1, %2" : "=v"(d3) : "v"(b.z), "v"(b.w));
    uint4 u; u.x = d0; u.y = d1; u.z = d2; u.w = d3;
    return __builtin_bit_cast(bf16x8, u);
}

static __device__ __forceinline__ void gl_lds16(const void* g, void* l) {
    __builtin_amdgcn_global_load_lds(
        (const __attribute__((address_space(1))) unsigned int*)g,
        (__attribute__((address_space(3))) unsigned int*)l, 16, 0, 0);
}

// ---- fused prologue: blocks [0,512) pack w -> wB frag layout;
//      blocks [512,2560) build adjacency bitmasks ----
__global__ __launch_bounds__(256) void k_prep(
    const float* __restrict__ w, unsigned short* __restrict__ wB,
    const float* __restrict__ adj, unsigned* __restrict__ mb)
{
    const int bid = blockIdx.x;
    if (bid < 512) {
        int gid = bid * 256 + threadIdx.x;
        int c = gid & 511, k = gid >> 9;
        int kb = k >> 5, g = (k >> 3) & 3, e = k & 7;
        wB[(((size_t)(kb * 4 + g) * 512) + c) * 8 + e] = f2bf(w[(size_t)k * 512 + c]);
    } else {
        const int lane = threadIdx.x & 63, wave = threadIdx.x >> 6;
        const int row0 = (bid - 512) * 8 + wave * 2;
        #pragma unroll
        for (int rr = 0; rr < 2; ++rr) {
            const float* arow = adj + (size_t)(row0 + rr) * NN;
            #pragma unroll
            for (int t = 0; t < 8; ++t) {
                unsigned long long msk = __ballot(arow[t * 64 + lane] > 0.f);
                if (lane == 0) {
                    mb[(size_t)(row0 + rr) * 16 + 2 * t]     = (unsigned)msk;
                    mb[(size_t)(row0 + rr) * 16 + 2 * t + 1] = (unsigned)(msk >> 32);
                }
            }
        }
    }
}

// ---- projection GEMM (MFMA): R6-proven 32 rows/block, 512 blocks; coeffs;
// hs staged directly in final slab order -> pure linear 8 KB copy per head.
// Slab order per (b,h,kb): short idx = nf*512 + g2*128 + l15*8 + e
//   (d = nf*16+l15, j = kb*32 + g2*8 + e).
__global__ __launch_bounds__(256) void k_proj(
    const float* __restrict__ x, const unsigned short* __restrict__ wB,
    const float* __restrict__ ai, const float* __restrict__ aj,
    unsigned short* __restrict__ hB, float* __restrict__ ciT, float* __restrict__ cjT)
{
    __shared__ unsigned short hs[NH * 4096];           // 32 KB, full-slab image
    const int tid = threadIdx.x;
    const int lane = tid & 63, head = tid >> 6;
    const int l15 = lane & 15, g = lane >> 4;
    const int row0 = blockIdx.x * 32;

    f32x4 acc[2][8] = {};
    const float* xp0 = x + (size_t)(row0 + l15) * INF + g * 8;
    const float* xp1 = xp0 + 16 * INF;
    const unsigned short* bp = wB + ((size_t)g * 512 + head * 128 + l15) * 8;

    #pragma unroll
    for (int kb = 0; kb < 8; ++kb) {
        float4 f0 = *(const float4*)(xp0 + kb * 32);
        float4 f1 = *(const float4*)(xp0 + kb * 32 + 4);
        float4 f2 = *(const float4*)(xp1 + kb * 32);
        float4 f3 = *(const float4*)(xp1 + kb * 32 + 4);
        bf16x8 a0 = pk8(f0, f1);
        bf16x8 a1 = pk8(f2, f3);
        #pragma unroll
        for (int nf = 0; nf < 8; ++nf) {
            bf16x8 bv = *(const bf16x8*)(bp + (size_t)kb * 16384 + nf * 128);
            acc[0][nf] = __builtin_amdgcn_mfma_f32_16x16x32_bf16(a0, bv, acc[0][nf], 0, 0, 0);
            acc[1][nf] = __builtin_amdgcn_mfma_f32_16x16x32_bf16(a1, bv, acc[1][nf], 0, 0, 0);
        }
    }

    float aiv[8], ajv[8];
    #pragma unroll
    for (int nf = 0; nf < 8; ++nf) {
        aiv[nf] = ai[head * 128 + nf * 16 + l15];
        ajv[nf] = aj[head * 128 + nf * 16 + l15];
    }
    const int b = row0 >> 9;
    const int nloc0 = row0 & 511;
    const int kb2 = nloc0 >> 5;

    #pragma unroll
    for (int m = 0; m < 2; ++m) {
        float pi[4] = {0,0,0,0}, pj[4] = {0,0,0,0};
        #pragma unroll
        for (int nf = 0; nf < 8; ++nf)
            #pragma unroll
            for (int reg = 0; reg < 4; ++reg) {
                pi[reg] = fmaf(acc[m][nf][reg], aiv[nf], pi[reg]);
                pj[reg] = fmaf(acc[m][nf][reg], ajv[nf], pj[reg]);
            }
        #pragma unroll
        for (int reg = 0; reg < 4; ++reg) {
            #pragma unroll
            for (int off = 1; off < 16; off <<= 1) {
                pi[reg] += __shfl_xor(pi[reg], off);
                pj[reg] += __shfl_xor(pj[reg], off);
            }
        }
        if (l15 == 0) {
            #pragma unroll
            for (int reg = 0; reg < 4; ++reg) {
                int n = nloc0 + 16 * m + 4 * g + reg;
                ciT[((size_t)(head * BSZ + b) * NN) + n] = pi[reg];
                cjT[((size_t)(head * BSZ + b) * NN) + n] = pj[reg];
            }
        }
        // stage in FINAL slab order: jloc = 16m+4g+reg, g2 = jloc>>3, e = jloc&7
        #pragma unroll
        for (int reg = 0; reg < 4; ++reg) {
            int jloc = 16 * m + 4 * g + reg;
            int g2 = jloc >> 3, e = jloc & 7;
            #pragma unroll
            for (int nf = 0; nf < 8; ++nf)
                hs[head * 4096 + nf * 512 + g2 * 128 + l15 * 8 + e] =
                    f2bf(acc[m][nf][reg]);
        }
    }
    __syncthreads();
    {   // pure linear copy: per head one contiguous 8 KB slab (512 ushort8)
        ushort8* dst = (ushort8*)(hB + (((size_t)(b * 4 + head) * 16 + kb2) * 4096));
        const ushort8* src = (const ushort8*)(hs + head * 4096);
        #pragma unroll
        for (int it = 0; it < 8; ++it)
            dst[it * 64 + lane] = src[it * 64 + lane];
    }
}

// ---- fused attention: block = (b, head, 64 rows). B-slab staged once in LDS
// (double-buffered, global_load_lds) and shared by 4 waves. Per-lane P synthesis
// in A-frag layout; ones-MFMA row sums; 1/sum in epilogue. (unchanged control)
__global__ __launch_bounds__(256, 4) void k_attn(
    const unsigned short* __restrict__ hB, const float* __restrict__ ciT,
    const float* __restrict__ cjT, const unsigned* __restrict__ mb,
    const float* __restrict__ bias, float* __restrict__ out)
{
    __shared__ __align__(16) unsigned short Bst[2][4096];  // 16 KB double buffer
    __shared__ __align__(16) float cjh[NN];                // 2 KB
    __shared__ float cih[64];
    __shared__ unsigned maskS[64][17];                     // padded (17 odd)
    __shared__ float Mpart[4];

    const int tid = threadIdx.x;
    const int lane = tid & 63, wave = tid >> 6;
    const int l15 = lane & 15, g = lane >> 4;

    const int orig = blockIdx.x;                   // 1024 blocks, bijective
    const int swz = (orig & 7) * 128 + (orig >> 3);// XCD x -> b in {4x..4x+3}
    const int b  = swz >> 5;
    const int h  = (swz >> 3) & 3;
    const int i0 = (swz & 7) * 64;

    const char* gslab = (const char*)(hB + (size_t)(b * NH + h) * 65536);

    gl_lds16(gslab + wave * 2048 + lane * 16,        (char*)&Bst[0][0] + wave * 2048);
    gl_lds16(gslab + wave * 2048 + 1024 + lane * 16, (char*)&Bst[0][0] + wave * 2048 + 1024);

    {   // cj -> LDS + unmasked max (stabilizer upper bound)
        const float* src = cjT + (size_t)(h * BSZ + b) * NN;
        float v0 = src[tid], v1 = src[tid + 256];
        cjh[tid] = v0; cjh[tid + 256] = v1;
        float mv = fmaxf(v0, v1);
        #pragma unroll
        for (int off = 32; off; off >>= 1) mv = fmaxf(mv, __shfl_xor(mv, off));
        if (lane == 0) Mpart[wave] = mv;
        if (tid < 64) cih[tid] = ciT[(size_t)(h * BSZ + b) * NN + i0 + tid];
        uint4 m4 = ((const uint4*)(mb + ((size_t)b * NN + i0) * 16))[tid];
        int base = tid * 4, row = base >> 4, wi = base & 15;
        maskS[row][wi] = m4.x; maskS[row][wi + 1] = m4.y;
        maskS[row][wi + 2] = m4.z; maskS[row][wi + 3] = m4.w;
    }
    __syncthreads();

    const float M = fmaxf(fmaxf(Mpart[0], Mpart[1]), fmaxf(Mpart[2], Mpart[3]));
    const float bc = cih[wave * 16 + l15];
    float smx = bc + M;
    const float mrow = fmaxf(smx, NEG_SLOPE * smx);

    float bvv[8];
    #pragma unroll
    for (int nf = 0; nf < 8; ++nf) bvv[nf] = bias[h * 128 + nf * 16 + l15];

    bf16x8 ones;
    #pragma unroll
    for (int e = 0; e < 8; ++e) ones[e] = (short)0x3F80;

    f32x4 acc[8] = {};
    f32x4 accs = {};
    int cur = 0;
    const unsigned* mrowp = maskS[wave * 16 + l15];

    for (int kb = 0; kb < 16; ++kb) {
        if (kb < 15) {
            const char* gs = gslab + (size_t)(kb + 1) * 8192 + wave * 2048 + lane * 16;
            char* ld = (char*)&Bst[cur ^ 1][0] + wave * 2048;
            gl_lds16(gs, ld);
            gl_lds16(gs + 1024, ld + 1024);
        }

        float4 cva = *(const float4*)&cjh[kb * 32 + g * 8];
        float4 cvb = *(const float4*)&cjh[kb * 32 + g * 8 + 4];
        float cj8[8] = {cva.x, cva.y, cva.z, cva.w, cvb.x, cvb.y, cvb.z, cvb.w};
        unsigned byte = (mrowp[kb] >> (g * 8)) & 0xFFu;
        float p[8];
        #pragma unroll
        for (int e = 0; e < 8; ++e) {
            float s = bc + cj8[e];
            s = fmaxf(s, NEG_SLOPE * s);
            float pe = __expf(s - mrow);
            p[e] = ((byte >> e) & 1u) ? pe : 0.f;
        }
        unsigned d0, d1, d2, d3;
        asm("v_cvt_pk_bf16_f32 %0, %1, %2" : "=v"(d0) : "v"(p[0]), "v"(p[1]));
        asm("v_cvt_pk_bf16_f32 %0, %1, %2" : "=v"(d1) : "v"(p[2]), "v"(p[3]));
        asm("v_cvt_pk_bf16_f32 %0, %1, %2" : "=v"(d2) : "v"(p[4]), "v"(p[5]));
        asm("v_cvt_pk_bf16_f32 %0, %1, %2" : "=v"(d3) : "v"(p[6]), "v"(p[7]));
        uint4 u; u.x = d0; u.y = d1; u.z = d2; u.w = d3;
        bf16x8 av = __builtin_bit_cast(bf16x8, u);

        const char* bb = (const char*)&Bst[cur][0] + lane * 16;
        bf16x8 bfr[8];
        #pragma unroll
        for (int nf = 0; nf < 8; ++nf)
            bfr[nf] = *(const bf16x8*)(bb + nf * 1024);

        #pragma unroll
        for (int nf = 0; nf < 8; ++nf)
            acc[nf] = __builtin_amdgcn_mfma_f32_16x16x32_bf16(av, bfr[nf], acc[nf], 0, 0, 0);
        accs = __builtin_amdgcn_mfma_f32_16x16x32_bf16(av, ones, accs, 0, 0, 0);

        if (kb < 15) { __syncthreads(); cur ^= 1; }
    }

    #pragma unroll
    for (int reg = 0; reg < 4; ++reg) {
        float sum = accs[reg];
        float inv = sum > 0.f ? 1.f / sum : 0.f;
        const int i = i0 + wave * 16 + g * 4 + reg;
        #pragma unroll
        for (int nf = 0; nf < 8; ++nf) {
            int colg = h * 128 + nf * 16 + l15;
            out[(size_t)(b * NN + i) * HD + colg] = acc[nf][reg] * inv + bvv[nf];
        }
    }
}

extern "C" void kernel_launch(void* const* d_in, const int* in_sizes, int n_in,
                              void* d_out, int out_size, void* d_ws, size_t ws_size,
                              hipStream_t stream)
{
    const float* x    = (const float*)d_in[0];
    const float* adj  = (const float*)d_in[1];
    const float* w    = (const float*)d_in[2];
    const float* ai   = (const float*)d_in[3];
    const float* aj   = (const float*)d_in[4];
    const float* bias = (const float*)d_in[5];
    float* out = (float*)d_out;

    char* ws = (char*)d_ws;
    unsigned short* wB = (unsigned short*)ws;                       //   262,144 B
    unsigned short* hB = (unsigned short*)(ws + 262144);            // 16,777,216 B
    float* ciT         = (float*)(ws + 17039360);                   //   262,144 B
    float* cjT         = (float*)(ws + 17301504);                   //   262,144 B
    unsigned* mb       = (unsigned*)(ws + 17563648);                // 1,048,576 B

    k_prep<<<2560, 256, 0, stream>>>(w, wB, adj, mb);
    k_proj<<<BSZ * NN / 32, 256, 0, stream>>>(x, wB, ai, aj, hB, ciT, cjT);
    k_attn<<<BSZ * NH * (NN / 64), 256, 0, stream>>>(hB, ciT, cjT, mb, bias, out);
}